// Round 3
// baseline (809.280 us; speedup 1.0000x reference)
//
#include <hip/hip_runtime.h>

// VoxelHashTableFlowTraverse: 8-corner hash-grid lookup + trilinear blend,
// with spatial counting-sort of queries so feature gathers are temporally
// local (fetch each 480B feature row from HBM ~once instead of ~8-20x).
//
// Pipeline: zero hist -> count per-bin -> exclusive scan -> scatter sorted
// query indices -> main gather kernel in sorted order (writes to original
// output slots).

#define TABLE_MASK ((1u << 20) - 1u)
#define FEAT_DIM 120

// Spatial bins: 2x2x2 voxels per bin. Base voxel ranges (from BMIN/BMAX):
// bx in [-26,45], by in [-81,46], bz in [0,30]. Offsets give kx in [3,38],
// ky in [7,71], kz in [0,15]; dims 64 x 128 x 16 = 131072 bins.
#define NBINS_X 64
#define NBINS_Y 128
#define NBINS_Z 16
#define NBINS (NBINS_X * NBINS_Y * NBINS_Z)

typedef float f4 __attribute__((ext_vector_type(4)));

__device__ __forceinline__ int query_key(const float* __restrict__ qp, int q) {
    const float px = qp[3 * q + 0];
    const float py = qp[3 * q + 1];
    const float pz = qp[3 * q + 2];
    const int bx = (int)floorf(px / 0.1f);
    const int by = (int)floorf(py / 0.1f);
    const int bz = (int)floorf(pz / 0.1f);
    int kx = ((bx + 32) >> 1) & (NBINS_X - 1);
    int ky = ((by + 96) >> 1) & (NBINS_Y - 1);
    int kz = (bz >> 1) & (NBINS_Z - 1);
    return ((kx * NBINS_Y) + ky) * NBINS_Z + kz;
}

__global__ __launch_bounds__(256) void zero_hist_kernel(int* __restrict__ hist) {
    const int i = blockIdx.x * blockDim.x + threadIdx.x;
    if (i < NBINS) hist[i] = 0;
}

__global__ __launch_bounds__(256) void count_kernel(
    const float* __restrict__ qp, int* __restrict__ hist, int M)
{
    const int q = blockIdx.x * blockDim.x + threadIdx.x;
    if (q >= M) return;
    atomicAdd(&hist[query_key(qp, q)], 1);
}

__global__ __launch_bounds__(1024) void scan_kernel(
    const int* __restrict__ hist, int* __restrict__ offs)
{
    __shared__ int lds[1024];
    __shared__ int carry;
    if (threadIdx.x == 0) carry = 0;
    __syncthreads();
    for (int base = 0; base < NBINS; base += 1024) {
        const int v = hist[base + threadIdx.x];
        lds[threadIdx.x] = v;
        __syncthreads();
        // Hillis-Steele inclusive scan in LDS.
        for (int d = 1; d < 1024; d <<= 1) {
            int t = (threadIdx.x >= d) ? lds[threadIdx.x - d] : 0;
            __syncthreads();
            lds[threadIdx.x] += t;
            __syncthreads();
        }
        offs[base + threadIdx.x] = carry + lds[threadIdx.x] - v;  // exclusive
        __syncthreads();
        if (threadIdx.x == 1023) carry += lds[1023];
        __syncthreads();
    }
}

__global__ __launch_bounds__(256) void scatter_kernel(
    const float* __restrict__ qp, int* __restrict__ offs,
    int* __restrict__ sidx, int M)
{
    const int q = blockIdx.x * blockDim.x + threadIdx.x;
    if (q >= M) return;
    const int pos = atomicAdd(&offs[query_key(qp, q)], 1);
    sidx[pos] = q;
}

__global__ __launch_bounds__(256) void voxel_trilinear_kernel(
    const float* __restrict__ qp,      // [M,3]
    const float* __restrict__ feat,    // [n_vox,120]
    const int*   __restrict__ table,   // [2^20]
    const int*   __restrict__ sidx,    // [M] spatially sorted query ids
    float*       __restrict__ out,     // [M,120]
    int M)
{
    const int gid = blockIdx.x * blockDim.x + threadIdx.x;
    const int g = gid >> 5;        // sorted-order slot
    const int c = gid & 31;        // float4 chunk index within feature row
    if (g >= M) return;
    const int q = sidx[g];         // original query id (broadcast in group)
    const int ce = (c < 30) ? c : 29;

    const float px = qp[q * 3 + 0];
    const float py = qp[q * 3 + 1];
    const float pz = qp[q * 3 + 2];

    // Divide by 0.1f (not multiply by 10) to match reference rounding.
    const float gx = px / 0.1f;
    const float gy = py / 0.1f;
    const float gz = pz / 0.1f;
    const float flx = floorf(gx), fly = floorf(gy), flz = floorf(gz);
    const float rx = gx - flx, ry = gy - fly, rz = gz - flz;
    const int bx = (int)flx, by = (int)fly, bz = (int)flz;

    const unsigned hx0 = (unsigned)bx * 73856093u;
    const unsigned hy0 = (unsigned)by * 19349669u;
    const unsigned hz0 = (unsigned)bz * 83492791u;
    const unsigned hx1 = hx0 + 73856093u;
    const unsigned hy1 = hy0 + 19349669u;
    const unsigned hz1 = hz0 + 83492791u;

    // Corner order matches reference.
    unsigned h[8];
    h[0] = (hx0 + hy0 + hz0) & TABLE_MASK;
    h[1] = (hx1 + hy0 + hz0) & TABLE_MASK;
    h[2] = (hx0 + hy1 + hz0) & TABLE_MASK;
    h[3] = (hx0 + hy0 + hz1) & TABLE_MASK;
    h[4] = (hx1 + hy1 + hz0) & TABLE_MASK;
    h[5] = (hx1 + hy0 + hz1) & TABLE_MASK;
    h[6] = (hx0 + hy1 + hz1) & TABLE_MASK;
    h[7] = (hx1 + hy1 + hz1) & TABLE_MASK;

    int vidx[8];
#pragma unroll
    for (int k = 0; k < 8; ++k) vidx[k] = table[h[k]];

    const float sx = 1.0f - rx, sy = 1.0f - ry, sz = 1.0f - rz;
    float w[8];
    w[0] = sx * sy * sz;
    w[1] = rx * sy * sz;
    w[2] = sx * ry * sz;
    w[3] = sx * sy * rz;
    w[4] = rx * ry * sz;
    w[5] = rx * sy * rz;
    w[6] = sx * ry * rz;
    w[7] = rx * ry * rz;

    f4 acc = (f4)(0.0f);
#pragma unroll
    for (int k = 0; k < 8; ++k) {
        const int v = vidx[k] >= 0 ? vidx[k] : 0;
        const float wk = vidx[k] >= 0 ? w[k] : 0.0f;
        const f4 f = *reinterpret_cast<const f4*>(
            feat + (size_t)v * FEAT_DIM + ce * 4);
        acc += f * wk;
    }

    if (c < 30) {
        __builtin_nontemporal_store(
            acc, reinterpret_cast<f4*>(out + (size_t)q * FEAT_DIM + c * 4));
    }
}

extern "C" void kernel_launch(void* const* d_in, const int* in_sizes, int n_in,
                              void* d_out, int out_size, void* d_ws, size_t ws_size,
                              hipStream_t stream) {
    const float* qp    = (const float*)d_in[0];
    const float* feat  = (const float*)d_in[1];
    const int*   table = (const int*)d_in[2];
    float*       out   = (float*)d_out;

    const int M = in_sizes[0] / 3;

    // Workspace layout: hist[NBINS] | offs[NBINS] | sidx[M]
    int* hist = (int*)d_ws;
    int* offs = hist + NBINS;
    int* sidx = offs + NBINS;

    const int block = 256;

    zero_hist_kernel<<<(NBINS + block - 1) / block, block, 0, stream>>>(hist);
    count_kernel<<<(M + block - 1) / block, block, 0, stream>>>(qp, hist, M);
    scan_kernel<<<1, 1024, 0, stream>>>(hist, offs);
    scatter_kernel<<<(M + block - 1) / block, block, 0, stream>>>(qp, offs, sidx, M);

    const long long threads = (long long)M * 32;
    const int grid = (int)((threads + block - 1) / block);
    voxel_trilinear_kernel<<<grid, block, 0, stream>>>(qp, feat, table, sidx, out, M);
}

// Round 4
// 489.402 us; speedup vs baseline: 1.6536x; 1.6536x over previous
//
#include <hip/hip_runtime.h>

// VoxelHashTableFlowTraverse: 8-corner hash-grid lookup + trilinear blend,
// with spatial counting-sort of queries so feature gathers are temporally
// local. R3 fix: parallel 3-level scan (the single-block Hillis-Steele scan
// was ~400us on its own) + bijective XCD-aware block swizzle on the main
// kernel so each XCD's L2 sees a contiguous spatial region.

#define TABLE_MASK ((1u << 20) - 1u)
#define FEAT_DIM 120

// Spatial bins: 2x2x2 voxels per bin. 64 x 128 x 16 = 131072 bins.
#define NBINS_X 64
#define NBINS_Y 128
#define NBINS_Z 16
#define NBINS (NBINS_X * NBINS_Y * NBINS_Z)
#define SCAN_BLK 256
#define NBLOCKS_SCAN (NBINS / SCAN_BLK)   // 512

typedef float f4 __attribute__((ext_vector_type(4)));

__device__ __forceinline__ int query_key(const float* __restrict__ qp, int q) {
    const float px = qp[3 * q + 0];
    const float py = qp[3 * q + 1];
    const float pz = qp[3 * q + 2];
    const int bx = (int)floorf(px / 0.1f);
    const int by = (int)floorf(py / 0.1f);
    const int bz = (int)floorf(pz / 0.1f);
    int kx = ((bx + 32) >> 1) & (NBINS_X - 1);
    int ky = ((by + 96) >> 1) & (NBINS_Y - 1);
    int kz = (bz >> 1) & (NBINS_Z - 1);
    return ((kx * NBINS_Y) + ky) * NBINS_Z + kz;
}

__global__ __launch_bounds__(256) void zero_hist_kernel(int* __restrict__ hist) {
    const int i = blockIdx.x * blockDim.x + threadIdx.x;
    if (i < NBINS) hist[i] = 0;
}

__global__ __launch_bounds__(256) void count_kernel(
    const float* __restrict__ qp, int* __restrict__ hist, int M)
{
    const int q = blockIdx.x * blockDim.x + threadIdx.x;
    if (q >= M) return;
    atomicAdd(&hist[query_key(qp, q)], 1);
}

// K1: per-block sums of 256 hist entries -> bsum[512]
__global__ __launch_bounds__(SCAN_BLK) void blocksum_kernel(
    const int* __restrict__ hist, int* __restrict__ bsum)
{
    const int i = blockIdx.x * SCAN_BLK + threadIdx.x;
    int v = hist[i];
#pragma unroll
    for (int d = 32; d > 0; d >>= 1) v += __shfl_down(v, d, 64);
    __shared__ int ws[4];
    if ((threadIdx.x & 63) == 0) ws[threadIdx.x >> 6] = v;
    __syncthreads();
    if (threadIdx.x == 0) bsum[blockIdx.x] = ws[0] + ws[1] + ws[2] + ws[3];
}

// K2: single-block exclusive scan of bsum[512] (in place -> bsumx)
__global__ __launch_bounds__(512) void scan_bsum_kernel(
    const int* __restrict__ bsum, int* __restrict__ bsumx)
{
    __shared__ int lds[512];
    const int t = threadIdx.x;
    const int v = bsum[t];
    lds[t] = v;
    __syncthreads();
#pragma unroll
    for (int d = 1; d < 512; d <<= 1) {
        int tv = (t >= d) ? lds[t - d] : 0;
        __syncthreads();
        lds[t] += tv;
        __syncthreads();
    }
    bsumx[t] = lds[t] - v;   // exclusive
}

// K3: per-block local exclusive scan + block offset -> offs
__global__ __launch_bounds__(SCAN_BLK) void local_scan_kernel(
    const int* __restrict__ hist, const int* __restrict__ bsumx,
    int* __restrict__ offs)
{
    __shared__ int lds[SCAN_BLK];
    const int i = blockIdx.x * SCAN_BLK + threadIdx.x;
    const int t = threadIdx.x;
    const int v = hist[i];
    lds[t] = v;
    __syncthreads();
#pragma unroll
    for (int d = 1; d < SCAN_BLK; d <<= 1) {
        int tv = (t >= d) ? lds[t - d] : 0;
        __syncthreads();
        lds[t] += tv;
        __syncthreads();
    }
    offs[i] = bsumx[blockIdx.x] + lds[t] - v;   // exclusive global
}

__global__ __launch_bounds__(256) void scatter_kernel(
    const float* __restrict__ qp, int* __restrict__ offs,
    int* __restrict__ sidx, int M)
{
    const int q = blockIdx.x * blockDim.x + threadIdx.x;
    if (q >= M) return;
    const int pos = atomicAdd(&offs[query_key(qp, q)], 1);
    sidx[pos] = q;
}

__global__ __launch_bounds__(256) void voxel_trilinear_kernel(
    const float* __restrict__ qp,      // [M,3]
    const float* __restrict__ feat,    // [n_vox,120]
    const int*   __restrict__ table,   // [2^20]
    const int*   __restrict__ sidx,    // [M] spatially sorted query ids
    float*       __restrict__ out,     // [M,120]
    int M)
{
    // Bijective XCD-aware swizzle: XCD k (= blockIdx%8 under round-robin
    // dispatch) gets the contiguous chunk k of sorted-query space.
    const int nwg = gridDim.x;
    const int q8 = nwg >> 3, r8 = nwg & 7;
    const int xcd = blockIdx.x & 7, sub = blockIdx.x >> 3;
    const int wg = ((xcd < r8) ? xcd * (q8 + 1)
                               : r8 * (q8 + 1) + (xcd - r8) * q8) + sub;

    const int gid = wg * 256 + threadIdx.x;
    const int g = gid >> 5;        // sorted-order slot
    const int c = gid & 31;        // float4 chunk index within feature row
    if (g >= M) return;
    const int q = sidx[g];         // original query id (broadcast in group)
    const int ce = (c < 30) ? c : 29;

    const float px = qp[q * 3 + 0];
    const float py = qp[q * 3 + 1];
    const float pz = qp[q * 3 + 2];

    // Divide by 0.1f (not multiply by 10) to match reference rounding.
    const float gx = px / 0.1f;
    const float gy = py / 0.1f;
    const float gz = pz / 0.1f;
    const float flx = floorf(gx), fly = floorf(gy), flz = floorf(gz);
    const float rx = gx - flx, ry = gy - fly, rz = gz - flz;
    const int bx = (int)flx, by = (int)fly, bz = (int)flz;

    const unsigned hx0 = (unsigned)bx * 73856093u;
    const unsigned hy0 = (unsigned)by * 19349669u;
    const unsigned hz0 = (unsigned)bz * 83492791u;
    const unsigned hx1 = hx0 + 73856093u;
    const unsigned hy1 = hy0 + 19349669u;
    const unsigned hz1 = hz0 + 83492791u;

    // Corner order matches reference.
    unsigned h[8];
    h[0] = (hx0 + hy0 + hz0) & TABLE_MASK;
    h[1] = (hx1 + hy0 + hz0) & TABLE_MASK;
    h[2] = (hx0 + hy1 + hz0) & TABLE_MASK;
    h[3] = (hx0 + hy0 + hz1) & TABLE_MASK;
    h[4] = (hx1 + hy1 + hz0) & TABLE_MASK;
    h[5] = (hx1 + hy0 + hz1) & TABLE_MASK;
    h[6] = (hx0 + hy1 + hz1) & TABLE_MASK;
    h[7] = (hx1 + hy1 + hz1) & TABLE_MASK;

    int vidx[8];
#pragma unroll
    for (int k = 0; k < 8; ++k) vidx[k] = table[h[k]];

    const float sx = 1.0f - rx, sy = 1.0f - ry, sz = 1.0f - rz;
    float w[8];
    w[0] = sx * sy * sz;
    w[1] = rx * sy * sz;
    w[2] = sx * ry * sz;
    w[3] = sx * sy * rz;
    w[4] = rx * ry * sz;
    w[5] = rx * sy * rz;
    w[6] = sx * ry * rz;
    w[7] = rx * ry * rz;

    f4 acc = (f4)(0.0f);
#pragma unroll
    for (int k = 0; k < 8; ++k) {
        const int v = vidx[k] >= 0 ? vidx[k] : 0;
        const float wk = vidx[k] >= 0 ? w[k] : 0.0f;
        const f4 f = *reinterpret_cast<const f4*>(
            feat + (size_t)v * FEAT_DIM + ce * 4);
        acc += f * wk;
    }

    if (c < 30) {
        __builtin_nontemporal_store(
            acc, reinterpret_cast<f4*>(out + (size_t)q * FEAT_DIM + c * 4));
    }
}

extern "C" void kernel_launch(void* const* d_in, const int* in_sizes, int n_in,
                              void* d_out, int out_size, void* d_ws, size_t ws_size,
                              hipStream_t stream) {
    const float* qp    = (const float*)d_in[0];
    const float* feat  = (const float*)d_in[1];
    const int*   table = (const int*)d_in[2];
    float*       out   = (float*)d_out;

    const int M = in_sizes[0] / 3;

    // Workspace layout: hist[NBINS] | offs[NBINS] | bsum[512] | bsumx[512] | sidx[M]
    int* hist  = (int*)d_ws;
    int* offs  = hist + NBINS;
    int* bsum  = offs + NBINS;
    int* bsumx = bsum + NBLOCKS_SCAN;
    int* sidx  = bsumx + NBLOCKS_SCAN;

    const int block = 256;

    zero_hist_kernel<<<(NBINS + block - 1) / block, block, 0, stream>>>(hist);
    count_kernel<<<(M + block - 1) / block, block, 0, stream>>>(qp, hist, M);
    blocksum_kernel<<<NBLOCKS_SCAN, SCAN_BLK, 0, stream>>>(hist, bsum);
    scan_bsum_kernel<<<1, 512, 0, stream>>>(bsum, bsumx);
    local_scan_kernel<<<NBLOCKS_SCAN, SCAN_BLK, 0, stream>>>(hist, bsumx, offs);
    scatter_kernel<<<(M + block - 1) / block, block, 0, stream>>>(qp, offs, sidx, M);

    const long long threads = (long long)M * 32;
    const int grid = (int)((threads + block - 1) / block);
    voxel_trilinear_kernel<<<grid, block, 0, stream>>>(qp, feat, table, sidx, out, M);
}

// Round 5
// 480.334 us; speedup vs baseline: 1.6848x; 1.0189x over previous
//
#include <hip/hip_runtime.h>

// VoxelHashTableFlowTraverse: 8-corner hash-grid lookup + trilinear blend,
// with spatial counting-sort of queries so feature gathers are temporally
// local. R5: main kernel restructured for ILP (16 lanes/query, 8 floats per
// lane, 2 gathers in flight per corner per lane); scatter emits a packed
// sorted float4 {px,py,pz,bits(q)} so the main kernel has no dependent
// sidx->qp indirection; count caches the bin key for scatter.

#define TABLE_MASK ((1u << 20) - 1u)
#define FEAT_DIM 120

// Spatial bins: 2x2x2 voxels per bin. 64 x 128 x 16 = 131072 bins.
#define NBINS_X 64
#define NBINS_Y 128
#define NBINS_Z 16
#define NBINS (NBINS_X * NBINS_Y * NBINS_Z)
#define SCAN_BLK 256
#define NBLOCKS_SCAN (NBINS / SCAN_BLK)   // 512

typedef float f4 __attribute__((ext_vector_type(4)));

__device__ __forceinline__ int query_key_from_pt(float px, float py, float pz) {
    const int bx = (int)floorf(px / 0.1f);
    const int by = (int)floorf(py / 0.1f);
    const int bz = (int)floorf(pz / 0.1f);
    int kx = ((bx + 32) >> 1) & (NBINS_X - 1);
    int ky = ((by + 96) >> 1) & (NBINS_Y - 1);
    int kz = (bz >> 1) & (NBINS_Z - 1);
    return ((kx * NBINS_Y) + ky) * NBINS_Z + kz;
}

__global__ __launch_bounds__(256) void zero_hist_kernel(int* __restrict__ hist) {
    const int i = blockIdx.x * blockDim.x + threadIdx.x;
    if (i < NBINS) hist[i] = 0;
}

__global__ __launch_bounds__(256) void count_kernel(
    const float* __restrict__ qp, int* __restrict__ hist,
    int* __restrict__ key, int M)
{
    const int q = blockIdx.x * blockDim.x + threadIdx.x;
    if (q >= M) return;
    const int k = query_key_from_pt(qp[3 * q], qp[3 * q + 1], qp[3 * q + 2]);
    key[q] = k;
    atomicAdd(&hist[k], 1);
}

// K1: per-block sums of 256 hist entries -> bsum[512]
__global__ __launch_bounds__(SCAN_BLK) void blocksum_kernel(
    const int* __restrict__ hist, int* __restrict__ bsum)
{
    const int i = blockIdx.x * SCAN_BLK + threadIdx.x;
    int v = hist[i];
#pragma unroll
    for (int d = 32; d > 0; d >>= 1) v += __shfl_down(v, d, 64);
    __shared__ int ws[4];
    if ((threadIdx.x & 63) == 0) ws[threadIdx.x >> 6] = v;
    __syncthreads();
    if (threadIdx.x == 0) bsum[blockIdx.x] = ws[0] + ws[1] + ws[2] + ws[3];
}

// K2: single-block exclusive scan of bsum[512]
__global__ __launch_bounds__(512) void scan_bsum_kernel(
    const int* __restrict__ bsum, int* __restrict__ bsumx)
{
    __shared__ int lds[512];
    const int t = threadIdx.x;
    const int v = bsum[t];
    lds[t] = v;
    __syncthreads();
#pragma unroll
    for (int d = 1; d < 512; d <<= 1) {
        int tv = (t >= d) ? lds[t - d] : 0;
        __syncthreads();
        lds[t] += tv;
        __syncthreads();
    }
    bsumx[t] = lds[t] - v;   // exclusive
}

// K3: per-block local exclusive scan + block offset -> offs
__global__ __launch_bounds__(SCAN_BLK) void local_scan_kernel(
    const int* __restrict__ hist, const int* __restrict__ bsumx,
    int* __restrict__ offs)
{
    __shared__ int lds[SCAN_BLK];
    const int i = blockIdx.x * SCAN_BLK + threadIdx.x;
    const int t = threadIdx.x;
    const int v = hist[i];
    lds[t] = v;
    __syncthreads();
#pragma unroll
    for (int d = 1; d < SCAN_BLK; d <<= 1) {
        int tv = (t >= d) ? lds[t - d] : 0;
        __syncthreads();
        lds[t] += tv;
        __syncthreads();
    }
    offs[i] = bsumx[blockIdx.x] + lds[t] - v;   // exclusive global
}

__global__ __launch_bounds__(256) void scatter_kernel(
    const float* __restrict__ qp, const int* __restrict__ key,
    int* __restrict__ offs, f4* __restrict__ sq, int M)
{
    const int q = blockIdx.x * blockDim.x + threadIdx.x;
    if (q >= M) return;
    const int pos = atomicAdd(&offs[key[q]], 1);
    f4 s;
    s.x = qp[3 * q + 0];
    s.y = qp[3 * q + 1];
    s.z = qp[3 * q + 2];
    s.w = __int_as_float(q);
    sq[pos] = s;
}

__global__ __launch_bounds__(256) void voxel_trilinear_kernel(
    const f4*    __restrict__ sq,      // [M] sorted {px,py,pz,bits(q)}
    const float* __restrict__ feat,    // [n_vox,120]
    const int*   __restrict__ table,   // [2^20]
    float*       __restrict__ out,     // [M,120]
    int M)
{
    // Bijective XCD-aware swizzle (nwg not necessarily divisible by 8).
    const int nwg = gridDim.x;
    const int q8 = nwg >> 3, r8 = nwg & 7;
    const int xcd = blockIdx.x & 7, sub = blockIdx.x >> 3;
    const int wg = ((xcd < r8) ? xcd * (q8 + 1)
                               : r8 * (q8 + 1) + (xcd - r8) * q8) + sub;

    const int gid = wg * 256 + threadIdx.x;
    const int g = gid >> 4;        // sorted-order query slot (16 lanes each)
    const int l = gid & 15;        // lane within query group
    if (g >= M) return;
    const int le = (l < 15) ? l : 14;   // lane 15 duplicates chunk 14's loads

    const f4 s = sq[g];            // broadcast within 16-lane group
    const float px = s.x, py = s.y, pz = s.z;
    const int q = __float_as_int(s.w);

    // Divide by 0.1f (not multiply by 10) to match reference rounding.
    const float gx = px / 0.1f;
    const float gy = py / 0.1f;
    const float gz = pz / 0.1f;
    const float flx = floorf(gx), fly = floorf(gy), flz = floorf(gz);
    const float rx = gx - flx, ry = gy - fly, rz = gz - flz;
    const int bx = (int)flx, by = (int)fly, bz = (int)flz;

    const unsigned hx0 = (unsigned)bx * 73856093u;
    const unsigned hy0 = (unsigned)by * 19349669u;
    const unsigned hz0 = (unsigned)bz * 83492791u;
    const unsigned hx1 = hx0 + 73856093u;
    const unsigned hy1 = hy0 + 19349669u;
    const unsigned hz1 = hz0 + 83492791u;

    // Corner order matches reference.
    unsigned h[8];
    h[0] = (hx0 + hy0 + hz0) & TABLE_MASK;
    h[1] = (hx1 + hy0 + hz0) & TABLE_MASK;
    h[2] = (hx0 + hy1 + hz0) & TABLE_MASK;
    h[3] = (hx0 + hy0 + hz1) & TABLE_MASK;
    h[4] = (hx1 + hy1 + hz0) & TABLE_MASK;
    h[5] = (hx1 + hy0 + hz1) & TABLE_MASK;
    h[6] = (hx0 + hy1 + hz1) & TABLE_MASK;
    h[7] = (hx1 + hy1 + hz1) & TABLE_MASK;

    int vidx[8];
#pragma unroll
    for (int k = 0; k < 8; ++k) vidx[k] = table[h[k]];

    const float sx = 1.0f - rx, sy = 1.0f - ry, sz = 1.0f - rz;
    float w[8];
    w[0] = sx * sy * sz;
    w[1] = rx * sy * sz;
    w[2] = sx * ry * sz;
    w[3] = sx * sy * rz;
    w[4] = rx * ry * sz;
    w[5] = rx * sy * rz;
    w[6] = sx * ry * rz;
    w[7] = rx * ry * rz;

    // Each lane owns 8 floats (2 x float4): two independent gathers per
    // corner -> 16 loads in flight per thread.
    f4 acc0 = (f4)(0.0f), acc1 = (f4)(0.0f);
    const size_t off = (size_t)le * 8;
#pragma unroll
    for (int k = 0; k < 8; ++k) {
        const int v = vidx[k] >= 0 ? vidx[k] : 0;
        const float wk = vidx[k] >= 0 ? w[k] : 0.0f;
        const float* p = feat + (size_t)v * FEAT_DIM + off;
        const f4 fa = *reinterpret_cast<const f4*>(p);
        const f4 fb = *reinterpret_cast<const f4*>(p + 4);
        acc0 += fa * wk;
        acc1 += fb * wk;
    }

    if (l < 15) {
        float* po = out + (size_t)q * FEAT_DIM + l * 8;
        __builtin_nontemporal_store(acc0, reinterpret_cast<f4*>(po));
        __builtin_nontemporal_store(acc1, reinterpret_cast<f4*>(po + 4));
    }
}

extern "C" void kernel_launch(void* const* d_in, const int* in_sizes, int n_in,
                              void* d_out, int out_size, void* d_ws, size_t ws_size,
                              hipStream_t stream) {
    const float* qp    = (const float*)d_in[0];
    const float* feat  = (const float*)d_in[1];
    const int*   table = (const int*)d_in[2];
    float*       out   = (float*)d_out;

    const int M = in_sizes[0] / 3;

    // Workspace: hist[NBINS] | offs[NBINS] | bsum[512] | bsumx[512] |
    //            key[M] | sq[M] (float4, 16B-aligned: offset is 16B-divisible)
    int* hist  = (int*)d_ws;
    int* offs  = hist + NBINS;
    int* bsum  = offs + NBINS;
    int* bsumx = bsum + NBLOCKS_SCAN;
    int* key   = bsumx + NBLOCKS_SCAN;
    f4*  sq    = (f4*)(key + M);

    const int block = 256;

    zero_hist_kernel<<<(NBINS + block - 1) / block, block, 0, stream>>>(hist);
    count_kernel<<<(M + block - 1) / block, block, 0, stream>>>(qp, hist, key, M);
    blocksum_kernel<<<NBLOCKS_SCAN, SCAN_BLK, 0, stream>>>(hist, bsum);
    scan_bsum_kernel<<<1, 512, 0, stream>>>(bsum, bsumx);
    local_scan_kernel<<<NBLOCKS_SCAN, SCAN_BLK, 0, stream>>>(hist, bsumx, offs);
    scatter_kernel<<<(M + block - 1) / block, block, 0, stream>>>(qp, key, offs, sq, M);

    const long long threads = (long long)M * 16;
    const int grid = (int)((threads + block - 1) / block);
    voxel_trilinear_kernel<<<grid, block, 0, stream>>>(sq, feat, table, out, M);
}

// Round 6
// 407.541 us; speedup vs baseline: 1.9858x; 1.1786x over previous
//
#include <hip/hip_runtime.h>

// VoxelHashTableFlowTraverse: 8-corner hash-grid lookup + trilinear blend.
// R6: bin-centric main kernel. Queries are counting-sorted by 4x4x2-voxel
// bin; one block per bin stages the bin's 5x5x3=75-row feature neighborhood
// into LDS once (probing the hash table per neighborhood voxel, zero-filling
// empty slots), then all queries of the bin blend from LDS. This replaces
// 3.84 GB of L2 gather traffic (the ~13 TB/s wall that pinned R3-R5 at
// ~295us) with ~0.3 GB staging + LDS-bandwidth reads.

#define TABLE_MASK ((1u << 20) - 1u)
#define FEAT_DIM 120
#define ROW_STRIDE 124            // padded row (floats); 496B keeps 16B align
#define NROWS 75                  // 5 x 5 x 3 neighborhood rows
#define NCHUNK 30                 // 120 floats = 30 float4 per row

// Bins: 4x4x2 voxels. bx in [-26,45] -> kx=((bx+32)>>2) in [1,19] (<32);
// by in [-81,46] -> ky=((by+96)>>2) in [3,35] (<64); bz in [0,30] ->
// kz=(bz>>1) in [0,15]. Dims 32 x 64 x 16 = 32768 bins.
#define NBINS_X 32
#define NBINS_Y 64
#define NBINS_Z 16
#define NBINS (NBINS_X * NBINS_Y * NBINS_Z)
#define SCAN_BLK 256
#define NBLOCKS_SCAN (NBINS / SCAN_BLK)   // 128

typedef float f4 __attribute__((ext_vector_type(4)));

__device__ __forceinline__ int query_key_from_pt(float px, float py, float pz) {
    const int bx = (int)floorf(px / 0.1f);
    const int by = (int)floorf(py / 0.1f);
    const int bz = (int)floorf(pz / 0.1f);
    const int kx = ((bx + 32) >> 2) & (NBINS_X - 1);
    const int ky = ((by + 96) >> 2) & (NBINS_Y - 1);
    const int kz = (bz >> 1) & (NBINS_Z - 1);
    return ((kx * NBINS_Y) + ky) * NBINS_Z + kz;
}

__global__ __launch_bounds__(256) void zero_hist_kernel(int* __restrict__ hist) {
    const int i = blockIdx.x * blockDim.x + threadIdx.x;
    if (i < NBINS) hist[i] = 0;
}

__global__ __launch_bounds__(256) void count_kernel(
    const float* __restrict__ qp, int* __restrict__ hist,
    int* __restrict__ key, int M)
{
    const int q = blockIdx.x * blockDim.x + threadIdx.x;
    if (q >= M) return;
    const int k = query_key_from_pt(qp[3 * q], qp[3 * q + 1], qp[3 * q + 2]);
    key[q] = k;
    atomicAdd(&hist[k], 1);
}

__global__ __launch_bounds__(SCAN_BLK) void blocksum_kernel(
    const int* __restrict__ hist, int* __restrict__ bsum)
{
    const int i = blockIdx.x * SCAN_BLK + threadIdx.x;
    int v = hist[i];
#pragma unroll
    for (int d = 32; d > 0; d >>= 1) v += __shfl_down(v, d, 64);
    __shared__ int ws[4];
    if ((threadIdx.x & 63) == 0) ws[threadIdx.x >> 6] = v;
    __syncthreads();
    if (threadIdx.x == 0) bsum[blockIdx.x] = ws[0] + ws[1] + ws[2] + ws[3];
}

__global__ __launch_bounds__(NBLOCKS_SCAN) void scan_bsum_kernel(
    const int* __restrict__ bsum, int* __restrict__ bsumx)
{
    __shared__ int lds[NBLOCKS_SCAN];
    const int t = threadIdx.x;
    const int v = bsum[t];
    lds[t] = v;
    __syncthreads();
#pragma unroll
    for (int d = 1; d < NBLOCKS_SCAN; d <<= 1) {
        int tv = (t >= d) ? lds[t - d] : 0;
        __syncthreads();
        lds[t] += tv;
        __syncthreads();
    }
    bsumx[t] = lds[t] - v;   // exclusive
}

__global__ __launch_bounds__(SCAN_BLK) void local_scan_kernel(
    const int* __restrict__ hist, const int* __restrict__ bsumx,
    int* __restrict__ offs)
{
    __shared__ int lds[SCAN_BLK];
    const int i = blockIdx.x * SCAN_BLK + threadIdx.x;
    const int t = threadIdx.x;
    const int v = hist[i];
    lds[t] = v;
    __syncthreads();
#pragma unroll
    for (int d = 1; d < SCAN_BLK; d <<= 1) {
        int tv = (t >= d) ? lds[t - d] : 0;
        __syncthreads();
        lds[t] += tv;
        __syncthreads();
    }
    offs[i] = bsumx[blockIdx.x] + lds[t] - v;   // exclusive global
}

__global__ __launch_bounds__(256) void scatter_kernel(
    const float* __restrict__ qp, const int* __restrict__ key,
    int* __restrict__ offs, f4* __restrict__ sq, int M)
{
    const int q = blockIdx.x * blockDim.x + threadIdx.x;
    if (q >= M) return;
    const int pos = atomicAdd(&offs[key[q]], 1);
    f4 s;
    s.x = qp[3 * q + 0];
    s.y = qp[3 * q + 1];
    s.z = qp[3 * q + 2];
    s.w = __int_as_float(q);
    sq[pos] = s;
}

// Main: one block per bin. Stage 75-row neighborhood in LDS, then blend.
__global__ __launch_bounds__(512) void voxel_trilinear_kernel(
    const f4*    __restrict__ sq,      // [M] sorted {px,py,pz,bits(q)}
    const float* __restrict__ feat,    // [n_vox,120]
    const int*   __restrict__ table,   // [2^20]
    const int*   __restrict__ hist,    // [NBINS] bin counts
    const int*   __restrict__ offs,    // [NBINS] = bin_end after scatter
    float*       __restrict__ out)     // [M,120]
{
    // Bijective XCD-aware swizzle (NBINS % 8 == 0): each XCD gets a
    // contiguous run of bins -> staging fetches hit its own L2.
    const int wg = (blockIdx.x & 7) * (NBINS >> 3) + (blockIdx.x >> 3);

    const int cnt = hist[wg];
    if (cnt == 0) return;
    const int start = offs[wg] - cnt;   // scatter advanced offs to bin end

    const int binx = wg >> 10;            // / (64*16)
    const int biny = (wg >> 4) & 63;
    const int binz = wg & 15;
    const int vx0 = binx * 4 - 32;
    const int vy0 = biny * 4 - 96;
    const int vz0 = binz * 2;

    __shared__ int   vox[NROWS];
    __shared__ float rows[NROWS * ROW_STRIDE];   // 37.2 KB

    const int t = threadIdx.x;

    // Phase 1: probe hash table for the 75 neighborhood voxels.
    if (t < NROWS) {
        const int i = t / 15;            // x offset 0..4
        const int j = (t / 3) % 5;       // y offset 0..4
        const int k = t % 3;             // z offset 0..2
        const unsigned h = (unsigned)(vx0 + i) * 73856093u
                         + (unsigned)(vy0 + j) * 19349669u
                         + (unsigned)(vz0 + k) * 83492791u;
        vox[t] = table[h & TABLE_MASK];
    }
    __syncthreads();

    // Phase 2: copy rows into LDS (zero-fill empty slots -> maskless blend).
    for (int idx = t; idx < NROWS * NCHUNK; idx += 512) {
        const int row = idx / NCHUNK;
        const int chunk = idx - row * NCHUNK;
        const int v = vox[row];
        f4 val = (f4)(0.0f);
        if (v >= 0)
            val = *reinterpret_cast<const f4*>(feat + (size_t)v * FEAT_DIM + chunk * 4);
        *reinterpret_cast<f4*>(rows + row * ROW_STRIDE + chunk * 4) = val;
    }
    __syncthreads();

    // Phase 3: blend queries. 16 lanes per query, 32 query-groups per block.
    const int group = t >> 4;
    const int l = t & 15;

    for (int s = start + group; s < start + cnt; s += 32) {
        const f4 qv = sq[s];
        const float px = qv.x, py = qv.y, pz = qv.z;
        const int q = __float_as_int(qv.w);

        // Divide by 0.1f (not *10) to match reference rounding.
        const float gx = px / 0.1f;
        const float gy = py / 0.1f;
        const float gz = pz / 0.1f;
        const float flx = floorf(gx), fly = floorf(gy), flz = floorf(gz);
        const float rx = gx - flx, ry = gy - fly, rz = gz - flz;
        const int bx = (int)flx, by = (int)fly, bz = (int)flz;
        const int lx = (bx + 32) & 3;
        const int ly = (by + 96) & 3;
        const int lz = bz & 1;

        const float sxw = 1.0f - rx, syw = 1.0f - ry, szw = 1.0f - rz;
        // Corner order matches reference:
        // (0,0,0),(1,0,0),(0,1,0),(0,0,1),(1,1,0),(1,0,1),(0,1,1),(1,1,1)
        float w[8];
        w[0] = sxw * syw * szw;
        w[1] = rx  * syw * szw;
        w[2] = sxw * ry  * szw;
        w[3] = sxw * syw * rz;
        w[4] = rx  * ry  * szw;
        w[5] = rx  * syw * rz;
        w[6] = sxw * ry  * rz;
        w[7] = rx  * ry  * rz;
        const int CX[8] = {0, 1, 0, 0, 1, 1, 0, 1};
        const int CY[8] = {0, 0, 1, 0, 1, 0, 1, 1};
        const int CZ[8] = {0, 0, 0, 1, 0, 1, 1, 1};

        // Lane l accumulates float4 chunks l and l+14 of the 120-float row.
        f4 a0 = (f4)(0.0f), a1 = (f4)(0.0f);
#pragma unroll
        for (int k = 0; k < 8; ++k) {
            const int row = ((lx + CX[k]) * 5 + (ly + CY[k])) * 3 + (lz + CZ[k]);
            const float* rp = rows + row * ROW_STRIDE;
            const f4 fa = *reinterpret_cast<const f4*>(rp + l * 4);
            const f4 fb = *reinterpret_cast<const f4*>(rp + 56 + l * 4);
            a0 += fa * w[k];
            a1 += fb * w[k];
        }

        float* po = out + (size_t)q * FEAT_DIM;
        __builtin_nontemporal_store(a0, reinterpret_cast<f4*>(po + l * 4));
        if (l >= 2)
            __builtin_nontemporal_store(a1, reinterpret_cast<f4*>(po + 56 + l * 4));
    }
}

extern "C" void kernel_launch(void* const* d_in, const int* in_sizes, int n_in,
                              void* d_out, int out_size, void* d_ws, size_t ws_size,
                              hipStream_t stream) {
    const float* qp    = (const float*)d_in[0];
    const float* feat  = (const float*)d_in[1];
    const int*   table = (const int*)d_in[2];
    float*       out   = (float*)d_out;

    const int M = in_sizes[0] / 3;

    // Workspace: hist | offs | bsum | bsumx | key[M] | sq[M] (16B aligned)
    int* hist  = (int*)d_ws;
    int* offs  = hist + NBINS;
    int* bsum  = offs + NBINS;
    int* bsumx = bsum + NBLOCKS_SCAN;
    int* key   = bsumx + NBLOCKS_SCAN;
    f4*  sq    = (f4*)(key + M);

    const int block = 256;

    zero_hist_kernel<<<(NBINS + block - 1) / block, block, 0, stream>>>(hist);
    count_kernel<<<(M + block - 1) / block, block, 0, stream>>>(qp, hist, key, M);
    blocksum_kernel<<<NBLOCKS_SCAN, SCAN_BLK, 0, stream>>>(hist, bsum);
    scan_bsum_kernel<<<1, NBLOCKS_SCAN, 0, stream>>>(bsum, bsumx);
    local_scan_kernel<<<NBLOCKS_SCAN, SCAN_BLK, 0, stream>>>(hist, bsumx, offs);
    scatter_kernel<<<(M + block - 1) / block, block, 0, stream>>>(qp, key, offs, sq, M);

    voxel_trilinear_kernel<<<NBINS, 512, 0, stream>>>(sq, feat, table, hist, offs, out);
}

// Round 7
// 319.994 us; speedup vs baseline: 2.5290x; 1.2736x over previous
//
#include <hip/hip_runtime.h>

// VoxelHashTableFlowTraverse: 8-corner hash-grid lookup + trilinear blend.
// R7: single-pass binning into fixed-capacity padded bins (pos = atomicAdd;
// sq[key*C+pos]) replaces the 6-kernel counting sort (count/3-scan/scatter
// were ~180us, co-equal with the main kernel). Overflow beyond C goes to a
// list handled by a grid-stride direct-gather fixup kernel (normally 0 work)
// so correctness never depends on bin occupancy. Main kernel unchanged:
// one block per 4x4x2-voxel bin stages the 5x5x3=75-row feature
// neighborhood in LDS (zero-filled for empty hash slots), then all the
// bin's queries blend from LDS at LDS bandwidth.

#define TABLE_MASK ((1u << 20) - 1u)
#define FEAT_DIM 120
#define ROW_STRIDE 124            // padded row (floats); 496B keeps 16B align
#define NROWS 75                  // 5 x 5 x 3 neighborhood rows
#define NCHUNK 30                 // 120 floats = 30 float4 per row

// Bins: 4x4x2 voxels. bx in [-26,45] -> kx=((bx+32)>>2) in [1,19] (<32);
// by in [-81,46] -> ky=((by+96)>>2) in [3,35] (<64); bz in [0,30] ->
// kz=(bz>>1) in [0,15]. Dims 32 x 64 x 16 = 32768 bins.
#define NBINS_X 32
#define NBINS_Y 64
#define NBINS_Z 16
#define NBINS (NBINS_X * NBINS_Y * NBINS_Z)

typedef float f4 __attribute__((ext_vector_type(4)));

__device__ __forceinline__ int query_key_from_pt(float px, float py, float pz) {
    const int bx = (int)floorf(px / 0.1f);
    const int by = (int)floorf(py / 0.1f);
    const int bz = (int)floorf(pz / 0.1f);
    const int kx = ((bx + 32) >> 2) & (NBINS_X - 1);
    const int ky = ((by + 96) >> 2) & (NBINS_Y - 1);
    const int kz = (bz >> 1) & (NBINS_Z - 1);
    return ((kx * NBINS_Y) + ky) * NBINS_Z + kz;
}

__global__ __launch_bounds__(256) void zero_kernel(int* __restrict__ hist) {
    const int i = blockIdx.x * blockDim.x + threadIdx.x;
    if (i < NBINS + 1) hist[i] = 0;   // hist[NBINS] doubles as ovf_cnt
}

// Single-pass binning: compute key, bump per-bin counter, write packed
// {px,py,pz,bits(q)} into the bin's padded slot array (or overflow list).
__global__ __launch_bounds__(256) void bin_kernel(
    const float* __restrict__ qp, int* __restrict__ hist,
    f4* __restrict__ sq, f4* __restrict__ ovf, int C, int M)
{
    const int q = blockIdx.x * blockDim.x + threadIdx.x;
    if (q >= M) return;
    const float px = qp[3 * q + 0];
    const float py = qp[3 * q + 1];
    const float pz = qp[3 * q + 2];
    const int key = query_key_from_pt(px, py, pz);
    const int pos = atomicAdd(&hist[key], 1);
    f4 s;
    s.x = px; s.y = py; s.z = pz; s.w = __int_as_float(q);
    if (pos < C) {
        sq[(size_t)key * C + pos] = s;
    } else {
        const int o = atomicAdd(&hist[NBINS], 1);
        if (o < M) ovf[o] = s;
    }
}

// Main: one block per bin. Stage 75-row neighborhood in LDS, then blend.
__global__ __launch_bounds__(512) void voxel_trilinear_kernel(
    const f4*    __restrict__ sq,      // [NBINS*C] padded bin slots
    const float* __restrict__ feat,    // [n_vox,120]
    const int*   __restrict__ table,   // [2^20]
    const int*   __restrict__ hist,    // [NBINS] bin counts
    float*       __restrict__ out,     // [M,120]
    int C)
{
    // Bijective XCD-aware swizzle (NBINS % 8 == 0): each XCD gets a
    // contiguous run of bins -> staging fetches hit its own L2.
    const int wg = (blockIdx.x & 7) * (NBINS >> 3) + (blockIdx.x >> 3);

    int cnt = hist[wg];
    if (cnt == 0) return;
    if (cnt > C) cnt = C;              // overflow handled by ovf_kernel
    const size_t start = (size_t)wg * C;

    const int binx = wg >> 10;            // / (64*16)
    const int biny = (wg >> 4) & 63;
    const int binz = wg & 15;
    const int vx0 = binx * 4 - 32;
    const int vy0 = biny * 4 - 96;
    const int vz0 = binz * 2;

    __shared__ int   vox[NROWS];
    __shared__ float rows[NROWS * ROW_STRIDE];   // 37.2 KB

    const int t = threadIdx.x;

    // Phase 1: probe hash table for the 75 neighborhood voxels.
    if (t < NROWS) {
        const int i = t / 15;            // x offset 0..4
        const int j = (t / 3) % 5;       // y offset 0..4
        const int k = t % 3;             // z offset 0..2
        const unsigned h = (unsigned)(vx0 + i) * 73856093u
                         + (unsigned)(vy0 + j) * 19349669u
                         + (unsigned)(vz0 + k) * 83492791u;
        vox[t] = table[h & TABLE_MASK];
    }
    __syncthreads();

    // Phase 2: copy rows into LDS (zero-fill empty slots -> maskless blend).
    for (int idx = t; idx < NROWS * NCHUNK; idx += 512) {
        const int row = idx / NCHUNK;
        const int chunk = idx - row * NCHUNK;
        const int v = vox[row];
        f4 val = (f4)(0.0f);
        if (v >= 0)
            val = *reinterpret_cast<const f4*>(feat + (size_t)v * FEAT_DIM + chunk * 4);
        *reinterpret_cast<f4*>(rows + row * ROW_STRIDE + chunk * 4) = val;
    }
    __syncthreads();

    // Phase 3: blend queries. 16 lanes per query, 32 query-groups per block.
    const int group = t >> 4;
    const int l = t & 15;

    for (int s = group; s < cnt; s += 32) {
        const f4 qv = sq[start + s];
        const float px = qv.x, py = qv.y, pz = qv.z;
        const int q = __float_as_int(qv.w);

        // Divide by 0.1f (not *10) to match reference rounding.
        const float gx = px / 0.1f;
        const float gy = py / 0.1f;
        const float gz = pz / 0.1f;
        const float flx = floorf(gx), fly = floorf(gy), flz = floorf(gz);
        const float rx = gx - flx, ry = gy - fly, rz = gz - flz;
        const int bx = (int)flx, by = (int)fly, bz = (int)flz;
        const int lx = (bx + 32) & 3;
        const int ly = (by + 96) & 3;
        const int lz = bz & 1;

        const float sxw = 1.0f - rx, syw = 1.0f - ry, szw = 1.0f - rz;
        // Corner order matches reference:
        // (0,0,0),(1,0,0),(0,1,0),(0,0,1),(1,1,0),(1,0,1),(0,1,1),(1,1,1)
        float w[8];
        w[0] = sxw * syw * szw;
        w[1] = rx  * syw * szw;
        w[2] = sxw * ry  * szw;
        w[3] = sxw * syw * rz;
        w[4] = rx  * ry  * szw;
        w[5] = rx  * syw * rz;
        w[6] = sxw * ry  * rz;
        w[7] = rx  * ry  * rz;
        const int CX[8] = {0, 1, 0, 0, 1, 1, 0, 1};
        const int CY[8] = {0, 0, 1, 0, 1, 0, 1, 1};
        const int CZ[8] = {0, 0, 0, 1, 0, 1, 1, 1};

        // Lane l accumulates float4 chunks l and l+14 of the 120-float row.
        f4 a0 = (f4)(0.0f), a1 = (f4)(0.0f);
#pragma unroll
        for (int k = 0; k < 8; ++k) {
            const int row = ((lx + CX[k]) * 5 + (ly + CY[k])) * 3 + (lz + CZ[k]);
            const float* rp = rows + row * ROW_STRIDE;
            const f4 fa = *reinterpret_cast<const f4*>(rp + l * 4);
            const f4 fb = *reinterpret_cast<const f4*>(rp + 56 + l * 4);
            a0 += fa * w[k];
            a1 += fb * w[k];
        }

        float* po = out + (size_t)q * FEAT_DIM;
        __builtin_nontemporal_store(a0, reinterpret_cast<f4*>(po + l * 4));
        if (l >= 2)
            __builtin_nontemporal_store(a1, reinterpret_cast<f4*>(po + 56 + l * 4));
    }
}

// Overflow fixup: direct 16-lane gather per query, grid-stride. Normally
// ovf_cnt == 0 and every block exits after one load.
__global__ __launch_bounds__(256) void ovf_kernel(
    const f4*    __restrict__ ovf,
    const int*   __restrict__ hist,    // hist[NBINS] = ovf count
    const float* __restrict__ feat,
    const int*   __restrict__ table,
    float*       __restrict__ out,
    int M)
{
    int n = hist[NBINS];
    if (n > M) n = M;
    if (n == 0) return;

    const int nthreads = gridDim.x * 256;
    for (int i = blockIdx.x * 256 + threadIdx.x; i < n * 16; i += nthreads) {
        const int g = i >> 4;
        const int l = i & 15;
        const f4 qv = ovf[g];
        const float px = qv.x, py = qv.y, pz = qv.z;
        const int q = __float_as_int(qv.w);

        const float gx = px / 0.1f;
        const float gy = py / 0.1f;
        const float gz = pz / 0.1f;
        const float flx = floorf(gx), fly = floorf(gy), flz = floorf(gz);
        const float rx = gx - flx, ry = gy - fly, rz = gz - flz;
        const int bx = (int)flx, by = (int)fly, bz = (int)flz;

        const unsigned hx0 = (unsigned)bx * 73856093u;
        const unsigned hy0 = (unsigned)by * 19349669u;
        const unsigned hz0 = (unsigned)bz * 83492791u;
        const unsigned hx1 = hx0 + 73856093u;
        const unsigned hy1 = hy0 + 19349669u;
        const unsigned hz1 = hz0 + 83492791u;

        unsigned h[8];
        h[0] = (hx0 + hy0 + hz0) & TABLE_MASK;
        h[1] = (hx1 + hy0 + hz0) & TABLE_MASK;
        h[2] = (hx0 + hy1 + hz0) & TABLE_MASK;
        h[3] = (hx0 + hy0 + hz1) & TABLE_MASK;
        h[4] = (hx1 + hy1 + hz0) & TABLE_MASK;
        h[5] = (hx1 + hy0 + hz1) & TABLE_MASK;
        h[6] = (hx0 + hy1 + hz1) & TABLE_MASK;
        h[7] = (hx1 + hy1 + hz1) & TABLE_MASK;

        int vidx[8];
#pragma unroll
        for (int k = 0; k < 8; ++k) vidx[k] = table[h[k]];

        const float sxw = 1.0f - rx, syw = 1.0f - ry, szw = 1.0f - rz;
        float w[8];
        w[0] = sxw * syw * szw;
        w[1] = rx  * syw * szw;
        w[2] = sxw * ry  * szw;
        w[3] = sxw * syw * rz;
        w[4] = rx  * ry  * szw;
        w[5] = rx  * syw * rz;
        w[6] = sxw * ry  * rz;
        w[7] = rx  * ry  * rz;

        f4 a0 = (f4)(0.0f), a1 = (f4)(0.0f);
#pragma unroll
        for (int k = 0; k < 8; ++k) {
            const int v = vidx[k] >= 0 ? vidx[k] : 0;
            const float wk = vidx[k] >= 0 ? w[k] : 0.0f;
            const float* rp = feat + (size_t)v * FEAT_DIM;
            const f4 fa = *reinterpret_cast<const f4*>(rp + l * 4);
            const f4 fb = *reinterpret_cast<const f4*>(rp + 56 + l * 4);
            a0 += fa * wk;
            a1 += fb * wk;
        }

        float* po = out + (size_t)q * FEAT_DIM;
        __builtin_nontemporal_store(a0, reinterpret_cast<f4*>(po + l * 4));
        if (l >= 2)
            __builtin_nontemporal_store(a1, reinterpret_cast<f4*>(po + 56 + l * 4));
    }
}

extern "C" void kernel_launch(void* const* d_in, const int* in_sizes, int n_in,
                              void* d_out, int out_size, void* d_ws, size_t ws_size,
                              hipStream_t stream) {
    const float* qp    = (const float*)d_in[0];
    const float* feat  = (const float*)d_in[1];
    const int*   table = (const int*)d_in[2];
    float*       out   = (float*)d_out;

    const int M = in_sizes[0] / 3;

    // Workspace: hist[NBINS+1] (last = ovf count), pad to 16B | ovf[M] f4 |
    // sq[NBINS*C] f4. C adapted to ws_size, capped at 192 (active bins hold
    // ~112 +- 11 queries; overflow path keeps any C correct).
    int* hist = (int*)d_ws;
    f4*  ovf  = (f4*)((char*)d_ws + ((NBINS + 1) * sizeof(int) + 15 & ~15));
    f4*  sq   = ovf + M;

    const size_t fixed = ((NBINS + 1) * sizeof(int) + 15 & ~15) + (size_t)M * 16;
    size_t cap = (ws_size > fixed) ? (ws_size - fixed) / ((size_t)NBINS * 16) : 0;
    int C = (cap > 192) ? 192 : (int)cap;
    if (C < 1) C = 1;

    const int block = 256;
    zero_kernel<<<(NBINS + 1 + block - 1) / block, block, 0, stream>>>(hist);
    bin_kernel<<<(M + block - 1) / block, block, 0, stream>>>(qp, hist, sq, ovf, C, M);
    voxel_trilinear_kernel<<<NBINS, 512, 0, stream>>>(sq, feat, table, hist, out, C);
    ovf_kernel<<<512, 256, 0, stream>>>(ovf, hist, feat, table, out, M);
}